// Round 4
// baseline (3623.487 us; speedup 1.0000x reference)
//
#include <hip/hip_runtime.h>
#include <math.h>
#include <float.h>

#define NC 256
#define NT 2048
#define KNN 10

// ws layout (bytes), total 34,340,864 (~32.8 MB):
//   sq : double[8*2048]          @ 0          (131072)
//   A  : float [8*2048*256]      @ 131072     (16777216)  neighbor-part MLP:  x^T * W1^T
//   E  : float [8*2048*256]      @ 16908288   (16777216)  conv + Bc + (b_conv+b_mlp), layout [b][t][o]
//   nb : int   [8*2048*10]       @ 33685504   (655360)
#define SQ_OFF 0
#define A_OFF  131072
#define E_OFF  16908288
#define NB_OFF 33685504

// num_frms may be int32 or int64 depending on jax_enable_x64 in the harness.
// int64 values in [0,2048) have zero high words at odd int32 slots; genuine
// int32 randint(0,2048) data has nonzero odd slots w.p. 1-(1/2048)^4.
__device__ __forceinline__ int load_nf(const int* __restrict__ nf, int b) {
    bool is64 = (nf[1] == 0) & (nf[3] == 0) & (nf[5] == 0) & (nf[7] == 0);
    return is64 ? nf[2 * b] : nf[b];
}

// ---------------- kernel 1: sq[b][t] = sum_c x[b][c][t]^2 (fp64) ----------------
__global__ __launch_bounds__(256) void k_sq(const float* __restrict__ x, double* __restrict__ sq) {
    int b = blockIdx.x >> 3;
    int t = ((blockIdx.x & 7) << 8) + threadIdx.x;
    const float* xp = x + (size_t)b * NC * NT + t;
    double a = 0.0;
    for (int c = 0; c < NC; ++c) { double v = (double)xp[(size_t)c * NT]; a = fma(v, v, a); }
    sq[b * NT + t] = a;
}

// ---------------- kernel 2: A[b][t][o] = sum_c x[b][c][t] * W_mlp[o][c]  (neighbor half) ----------------
__global__ __launch_bounds__(256) void k_agemm(const float* __restrict__ x, const float* __restrict__ Wm,
                                               float* __restrict__ A) {
    __shared__ __align__(16) float Xs[64 * 68];
    __shared__ __align__(16) float Ws[64 * 68];
    int tx = blockIdx.x * 64;
    int oy = blockIdx.y * 64;      // 0..192
    int b = blockIdx.z;
    int tid = threadIdx.x;
    int tB = (tid >> 4) * 4;
    int oB = (tid & 15) * 4;
    float acc[4][4] = {};
    for (int c0 = 0; c0 < 256; c0 += 64) {
        __syncthreads();
        #pragma unroll
        for (int i = 0; i < 16; ++i) {
            int idx = tid + i * 256;
            int hi = idx >> 6, lo = idx & 63;            // lo varies with lane -> coalesced
            Xs[hi * 68 + lo] = x[((size_t)b * NC + c0 + hi) * NT + tx + lo];
            Ws[lo * 68 + hi] = Wm[(size_t)(oy + hi) * 512 + c0 + lo];   // Ws[c][o]
        }
        __syncthreads();
        #pragma unroll 8
        for (int cc = 0; cc < 64; ++cc) {
            float4 xa = *(const float4*)&Xs[cc * 68 + tB];
            float4 wb = *(const float4*)&Ws[cc * 68 + oB];
            float xv[4] = {xa.x, xa.y, xa.z, xa.w};
            float wv[4] = {wb.x, wb.y, wb.z, wb.w};
            #pragma unroll
            for (int i = 0; i < 4; ++i)
                #pragma unroll
                for (int j = 0; j < 4; ++j) acc[i][j] += xv[i] * wv[j];
        }
    }
    for (int i = 0; i < 4; ++i) {
        float4 v = {acc[i][0], acc[i][1], acc[i][2], acc[i][3]};
        *(float4*)&A[((size_t)b * NT + tx + tB + i) * 256 + oy + oB] = v;
    }
}

// ---------------- kernel 3: E[b][t][o] = conv1d(x,W_conv,pad=1) + Bc + (b_conv + b_mlp) ----------------
// Bc (center-feature MLP half) is folded into the conv's center tap: W'[o][c][1] = Wc[o][c][1] + Wm[o][256+c]
__global__ __launch_bounds__(256) void k_conv(const float* __restrict__ x, const float* __restrict__ Wc,
                                              const float* __restrict__ bc, const float* __restrict__ Wm,
                                              const float* __restrict__ bm, float* __restrict__ E) {
    __shared__ __align__(16) float Xs[32 * 72];     // [c][66 halo]
    __shared__ __align__(16) float Ws[96 * 68];     // [(c*3+kh)][o]
    int tx = blockIdx.x * 64;
    int oy = blockIdx.y * 64;
    int b = blockIdx.z;
    int tid = threadIdx.x;
    int tB = (tid >> 4) * 4;
    int oB = (tid & 15) * 4;
    float acc[4][4] = {};
    for (int c0 = 0; c0 < 256; c0 += 32) {
        __syncthreads();
        #pragma unroll
        for (int i = 0; i < 9; ++i) {
            int idx = tid + i * 256;
            if (idx < 32 * 66) {
                int c = idx / 66, j = idx % 66;
                int g = tx - 1 + j;
                float v = (g >= 0 && g < NT) ? x[((size_t)b * NC + c0 + c) * NT + g] : 0.f;
                Xs[c * 72 + j] = v;
            }
        }
        #pragma unroll
        for (int i = 0; i < 24; ++i) {
            int idx = tid + i * 256;
            int j = idx / 96, rem = idx % 96;     // rem = c*3+kh, coalesced in global
            float w = Wc[(size_t)(oy + j) * 768 + c0 * 3 + rem];
            if (rem % 3 == 1)                     // center tap: fold in W_mlp[o][256+c]
                w += Wm[(size_t)(oy + j) * 512 + 256 + c0 + (rem - 1) / 3];
            Ws[rem * 68 + j] = w;
        }
        __syncthreads();
        #pragma unroll 4
        for (int cc = 0; cc < 32; ++cc) {
            float xs[6];
            float4 a = *(const float4*)&Xs[cc * 72 + tB];
            float2 a2 = *(const float2*)&Xs[cc * 72 + tB + 4];
            xs[0] = a.x; xs[1] = a.y; xs[2] = a.z; xs[3] = a.w; xs[4] = a2.x; xs[5] = a2.y;
            #pragma unroll
            for (int kh = 0; kh < 3; ++kh) {
                float4 w = *(const float4*)&Ws[(cc * 3 + kh) * 68 + oB];
                float wv[4] = {w.x, w.y, w.z, w.w};
                #pragma unroll
                for (int tt = 0; tt < 4; ++tt)
                    #pragma unroll
                    for (int oo = 0; oo < 4; ++oo) acc[tt][oo] += xs[tt + kh] * wv[oo];
            }
        }
    }
    for (int tt = 0; tt < 4; ++tt) {
        float4 v;
        float* vv = (float*)&v;
        #pragma unroll
        for (int oo = 0; oo < 4; ++oo) {
            int o = oy + oB + oo;
            vv[oo] = acc[tt][oo] + bc[o] + bm[o];
        }
        *(float4*)&E[((size_t)b * NT + tx + tB + tt) * 256 + oy + oB] = v;
    }
}

// wave-level sorted-top10 insert scan. All 64 lanes execute; list in LDS (volatile).
// Preserves jax.lax.top_k tie semantics: keys processed in ascending j, strict < for entry,
// ties with existing (lower-j) entries lose.
__device__ __forceinline__ void topk_scan(const double* __restrict__ Dfrow, int jbase,
                                          unsigned long long validmask,
                                          volatile double* val, volatile int* idx, int lane) {
    double d = Dfrow[lane];
    double m10 = val[9];
    unsigned long long mask = __ballot(d < m10) & validmask;
    int guard = 0;
    while (mask && guard < 64) {
        ++guard;
        int bit = __ffsll((unsigned long long)mask) - 1;
        mask &= mask - 1;
        double vv = Dfrow[bit];         // uniform broadcast read
        double cur9 = val[9];
        if (!(vv < cur9)) continue;     // list tightened since ballot
        int jj = jbase + bit;
        double ev = (lane < 10) ? val[lane] : 0.0;
        int ej = (lane < 10) ? idx[lane] : 0;
        unsigned long long le = __ballot((lane < 10) && (ev <= vv));
        int pos = __popcll(le);
        double pv = (lane >= 1 && lane < 10) ? val[lane - 1] : 0.0;
        int pj = (lane >= 1 && lane < 10) ? idx[lane - 1] : 0;
        if (lane < 10) {
            val[lane] = (lane < pos) ? ev : ((lane == pos) ? vv : pv);
            idx[lane] = (lane < pos) ? ej : ((lane == pos) ? jj : pj);
        }
    }
}

// ---------------- kernel 4: fp64 distances + unrestricted top-10 per row ----------------
__global__ __launch_bounds__(256) void k_knn(const float* __restrict__ x, const double* __restrict__ sq,
                                             int* __restrict__ nb) {
    __shared__ __align__(16) float Xq[256 * 32];
    __shared__ __align__(16) float Xk[32 * 64];
    __shared__ __align__(16) double Df[32 * 64];
    __shared__ double Lv[32 * 10];
    __shared__ int Li[32 * 10];
    __shared__ double Sq[32];
    __shared__ double Sk[64];
    int q0 = blockIdx.x * 32;
    int b = blockIdx.y;
    int tid = threadIdx.x;
    int lane = tid & 63, wave = tid >> 6;
    for (int i = tid; i < 320; i += 256) { Lv[i] = INFINITY; Li[i] = 0; }
    if (tid < 32) Sq[tid] = sq[b * NT + q0 + tid];
    #pragma unroll
    for (int i = 0; i < 32; ++i) {
        int idx = tid + i * 256;
        int c = idx >> 5, q = idx & 31;
        Xq[c * 32 + q] = x[((size_t)b * NC + c) * NT + q0 + q];
    }
    __syncthreads();
    int qB = (tid >> 4) * 2;
    int kB = (tid & 15) * 4;
    for (int k0 = 0; k0 < NT; k0 += 64) {
        double acc[2][4] = {};
        if (tid < 64) Sk[tid] = sq[b * NT + k0 + tid];
        for (int cb = 0; cb < 256; cb += 32) {
            __syncthreads();
            #pragma unroll
            for (int i = 0; i < 8; ++i) {
                int idx = tid + i * 256;
                int c = idx >> 6, k = idx & 63;
                Xk[c * 64 + k] = x[((size_t)b * NC + cb + c) * NT + k0 + k];
            }
            __syncthreads();
            #pragma unroll 8
            for (int cc = 0; cc < 32; ++cc) {
                float2 xq = *(const float2*)&Xq[(cb + cc) * 32 + qB];
                float4 xk = *(const float4*)&Xk[cc * 64 + kB];
                double q0d = (double)xq.x, q1d = (double)xq.y;
                double kd[4] = {(double)xk.x, (double)xk.y, (double)xk.z, (double)xk.w};
                #pragma unroll
                for (int j = 0; j < 4; ++j) {
                    acc[0][j] = fma(q0d, kd[j], acc[0][j]);
                    acc[1][j] = fma(q1d, kd[j], acc[1][j]);
                }
            }
        }
        #pragma unroll
        for (int i = 0; i < 2; ++i)
            #pragma unroll
            for (int j = 0; j < 4; ++j)
                Df[(qB + i) * 64 + kB + j] = Sq[qB + i] + Sk[kB + j] - 2.0 * acc[i][j];
        __syncthreads();
        for (int rr = 0; rr < 8; ++rr) {
            int r = wave * 8 + rr;
            topk_scan(&Df[r * 64], k0, ~0ull, &Lv[r * 10], &Li[r * 10], lane);
        }
        __syncthreads();
    }
    // 320 entries, 256 threads -> strided loop (BUG FIX: was `if (tid < 320)`,
    // which silently dropped entries 256..319 = rows 25..31 of every block)
    for (int i = tid; i < 320; i += 256)
        nb[((size_t)b * NT + q0 + i / 10) * 10 + (i % 10)] = Li[i];
}

// ---------------- kernel 4b: restricted re-selection for short batches, rows i >= thr ----------------
__global__ __launch_bounds__(256) void k_knn2(const float* __restrict__ x, const double* __restrict__ sq,
                                              const int* __restrict__ nf, int* __restrict__ nb) {
    __shared__ __align__(16) float Xq[256 * 32];
    __shared__ __align__(16) float Xk[32 * 64];
    __shared__ __align__(16) double Df[32 * 64];
    __shared__ double Lv[32 * 10];
    __shared__ int Li[32 * 10];
    __shared__ double Sq[32];
    __shared__ double Sk[64];
    int b = blockIdx.y;
    int n = load_nf(nf, b);
    if (n > 819) return;               // cond: num_frms <= 0.4*2048 = 819.2
    int thr = n + 20;                  // ratio == 1
    int q0 = blockIdx.x * 32;
    if (q0 + 31 < thr) return;         // no row i >= thr in this block
    int tid = threadIdx.x;
    int lane = tid & 63, wave = tid >> 6;
    for (int i = tid; i < 320; i += 256) { Lv[i] = INFINITY; Li[i] = 0; }
    if (tid < 32) Sq[tid] = sq[b * NT + q0 + tid];
    #pragma unroll
    for (int i = 0; i < 32; ++i) {
        int idx = tid + i * 256;
        int c = idx >> 5, q = idx & 31;
        Xq[c * 32 + q] = x[((size_t)b * NC + c) * NT + q0 + q];
    }
    __syncthreads();
    int qB = (tid >> 4) * 2;
    int kB = (tid & 15) * 4;
    for (int k0 = 0; k0 < thr; k0 += 64) {
        double acc[2][4] = {};
        if (tid < 64) Sk[tid] = sq[b * NT + k0 + tid];
        for (int cb = 0; cb < 256; cb += 32) {
            __syncthreads();
            #pragma unroll
            for (int i = 0; i < 8; ++i) {
                int idx = tid + i * 256;
                int c = idx >> 6, k = idx & 63;
                Xk[c * 64 + k] = x[((size_t)b * NC + cb + c) * NT + k0 + k];
            }
            __syncthreads();
            #pragma unroll 8
            for (int cc = 0; cc < 32; ++cc) {
                float2 xq = *(const float2*)&Xq[(cb + cc) * 32 + qB];
                float4 xk = *(const float4*)&Xk[cc * 64 + kB];
                double q0d = (double)xq.x, q1d = (double)xq.y;
                double kd[4] = {(double)xk.x, (double)xk.y, (double)xk.z, (double)xk.w};
                #pragma unroll
                for (int j = 0; j < 4; ++j) {
                    acc[0][j] = fma(q0d, kd[j], acc[0][j]);
                    acc[1][j] = fma(q1d, kd[j], acc[1][j]);
                }
            }
        }
        #pragma unroll
        for (int i = 0; i < 2; ++i)
            #pragma unroll
            for (int j = 0; j < 4; ++j)
                Df[(qB + i) * 64 + kB + j] = Sq[qB + i] + Sk[kB + j] - 2.0 * acc[i][j];
        __syncthreads();
        // validity: key j (= k0+lane) must be < thr
        unsigned long long vm = __ballot((k0 + lane) < thr);
        for (int rr = 0; rr < 8; ++rr) {
            int r = wave * 8 + rr;
            topk_scan(&Df[r * 64], k0, vm, &Lv[r * 10], &Li[r * 10], lane);
        }
        __syncthreads();
    }
    // rows i >= thr: drop entries matching first-5 of the unrestricted list, write next 5 as tail
    for (int rr = 0; rr < 8; ++rr) {
        int r = wave * 8 + rr;
        int i = q0 + r;
        if (i >= thr) {
            int e = (lane < 10) ? Li[r * 10 + lane] : -1;
            bool keep = lane < 10;
            #pragma unroll
            for (int s = 0; s < 5; ++s) {
                int f = nb[((size_t)b * NT + i) * 10 + s];
                keep = keep && (e != f);
            }
            unsigned long long km = __ballot(keep);
            int rank = __popcll(km & ((1ull << lane) - 1ull));
            if (keep && rank < 5) nb[((size_t)b * NT + i) * 10 + 5 + rank] = e;
        }
    }
}

// ---------------- kernel 5: epilogue — gather-max + E add + relu + pair max-pool ----------------
__global__ __launch_bounds__(256) void k_epi(const float* __restrict__ A, const float* __restrict__ E,
                                             const int* __restrict__ nb, float* __restrict__ out) {
    __shared__ float buf[256 * 33];
    int p0 = blockIdx.x * 32;
    int b = blockIdx.y;
    int o = threadIdx.x;
    for (int pp = 0; pp < 32; ++pp) {
        int p = p0 + pp;
        float vmax = 0.f;
        #pragma unroll
        for (int tt = 0; tt < 2; ++tt) {
            int t = p * 2 + tt;
            const int* nrow = &nb[((size_t)b * NT + t) * 10];
            float gm = -FLT_MAX;
            #pragma unroll
            for (int k = 0; k < 10; ++k) {
                int t2 = nrow[k] & (NT - 1);   // safety clamp
                gm = fmaxf(gm, A[((size_t)b * NT + t2) * 256 + o]);
            }
            float v = E[((size_t)b * NT + t) * 256 + o] + gm;
            v = fmaxf(v, 0.f);
            vmax = (tt == 0) ? v : fmaxf(vmax, v);
        }
        buf[o * 33 + pp] = vmax;
    }
    __syncthreads();
    #pragma unroll
    for (int i = 0; i < 32; ++i) {
        int idx = threadIdx.x + i * 256;
        int oo = idx >> 5, pp = idx & 31;
        out[((size_t)b * 256 + oo) * 1024 + p0 + pp] = buf[oo * 33 + pp];
    }
}

extern "C" void kernel_launch(void* const* d_in, const int* in_sizes, int n_in,
                              void* d_out, int out_size, void* d_ws, size_t ws_size,
                              hipStream_t stream) {
    const float* x  = (const float*)d_in[0];
    const int*   nf = (const int*)d_in[1];
    const float* Wc = (const float*)d_in[2];
    const float* bc = (const float*)d_in[3];
    const float* Wm = (const float*)d_in[4];
    const float* bm = (const float*)d_in[5];
    float* out = (float*)d_out;
    char* ws = (char*)d_ws;
    double* sq = (double*)(ws + SQ_OFF);
    float* A   = (float*)(ws + A_OFF);
    float* E   = (float*)(ws + E_OFF);
    int* nb    = (int*)(ws + NB_OFF);

    k_sq<<<dim3(64), dim3(256), 0, stream>>>(x, sq);
    k_agemm<<<dim3(32, 4, 8), dim3(256), 0, stream>>>(x, Wm, A);
    k_conv<<<dim3(32, 4, 8), dim3(256), 0, stream>>>(x, Wc, bc, Wm, bm, E);
    k_knn<<<dim3(64, 8), dim3(256), 0, stream>>>(x, sq, nb);
    k_knn2<<<dim3(64, 8), dim3(256), 0, stream>>>(x, sq, nf, nb);
    k_epi<<<dim3(32, 8), dim3(256), 0, stream>>>(A, E, nb, out);
}

// Round 6
// 1429.656 us; speedup vs baseline: 2.5345x; 2.5345x over previous
//
#include <hip/hip_runtime.h>
#include <math.h>
#include <float.h>

#define NC 256
#define NT 2048
#define KNN 10

typedef __attribute__((ext_vector_type(4))) double dbl4;

// ws layout (bytes), total 34,340,864 (~32.8 MB):
#define SQ_OFF 0
#define A_OFF  131072
#define E_OFF  16908288
#define NB_OFF 33685504

// num_frms may be int32 or int64 depending on jax_enable_x64 in the harness.
__device__ __forceinline__ int load_nf(const int* __restrict__ nf, int b) {
    bool is64 = (nf[1] == 0) & (nf[3] == 0) & (nf[5] == 0) & (nf[7] == 0);
    return is64 ? nf[2 * b] : nf[b];
}

// ---------------- kernel 1: sq[b][t] = sum_c x[b][c][t]^2 (fp64) ----------------
__global__ __launch_bounds__(256) void k_sq(const float* __restrict__ x, double* __restrict__ sq) {
    int b = blockIdx.x >> 3;
    int t = ((blockIdx.x & 7) << 8) + threadIdx.x;
    const float* xp = x + (size_t)b * NC * NT + t;
    double a = 0.0;
    for (int c = 0; c < NC; ++c) { double v = (double)xp[(size_t)c * NT]; a = fma(v, v, a); }
    sq[b * NT + t] = a;
}

// ---------------- kernel 2: A[b][t][o] = sum_c x[b][c][t] * W_mlp[o][c]  (neighbor half) ----------------
__global__ __launch_bounds__(256) void k_agemm(const float* __restrict__ x, const float* __restrict__ Wm,
                                               float* __restrict__ A) {
    __shared__ __align__(16) float Xs[64 * 68];
    __shared__ __align__(16) float Ws[64 * 68];
    int tx = blockIdx.x * 64;
    int oy = blockIdx.y * 64;
    int b = blockIdx.z;
    int tid = threadIdx.x;
    int tB = (tid >> 4) * 4;
    int oB = (tid & 15) * 4;
    float acc[4][4] = {};
    for (int c0 = 0; c0 < 256; c0 += 64) {
        __syncthreads();
        #pragma unroll
        for (int i = 0; i < 16; ++i) {
            int idx = tid + i * 256;
            int hi = idx >> 6, lo = idx & 63;
            Xs[hi * 68 + lo] = x[((size_t)b * NC + c0 + hi) * NT + tx + lo];
            Ws[lo * 68 + hi] = Wm[(size_t)(oy + hi) * 512 + c0 + lo];
        }
        __syncthreads();
        #pragma unroll 8
        for (int cc = 0; cc < 64; ++cc) {
            float4 xa = *(const float4*)&Xs[cc * 68 + tB];
            float4 wb = *(const float4*)&Ws[cc * 68 + oB];
            float xv[4] = {xa.x, xa.y, xa.z, xa.w};
            float wv[4] = {wb.x, wb.y, wb.z, wb.w};
            #pragma unroll
            for (int i = 0; i < 4; ++i)
                #pragma unroll
                for (int j = 0; j < 4; ++j) acc[i][j] += xv[i] * wv[j];
        }
    }
    for (int i = 0; i < 4; ++i) {
        float4 v = {acc[i][0], acc[i][1], acc[i][2], acc[i][3]};
        *(float4*)&A[((size_t)b * NT + tx + tB + i) * 256 + oy + oB] = v;
    }
}

// ---------------- kernel 3: E[b][t][o] = conv1d + folded center-tap MLP half + biases ----------------
__global__ __launch_bounds__(256) void k_conv(const float* __restrict__ x, const float* __restrict__ Wc,
                                              const float* __restrict__ bc, const float* __restrict__ Wm,
                                              const float* __restrict__ bm, float* __restrict__ E) {
    __shared__ __align__(16) float Xs[32 * 72];
    __shared__ __align__(16) float Ws[96 * 68];
    int tx = blockIdx.x * 64;
    int oy = blockIdx.y * 64;
    int b = blockIdx.z;
    int tid = threadIdx.x;
    int tB = (tid >> 4) * 4;
    int oB = (tid & 15) * 4;
    float acc[4][4] = {};
    for (int c0 = 0; c0 < 256; c0 += 32) {
        __syncthreads();
        #pragma unroll
        for (int i = 0; i < 9; ++i) {
            int idx = tid + i * 256;
            if (idx < 32 * 66) {
                int c = idx / 66, j = idx % 66;
                int g = tx - 1 + j;
                float v = (g >= 0 && g < NT) ? x[((size_t)b * NC + c0 + c) * NT + g] : 0.f;
                Xs[c * 72 + j] = v;
            }
        }
        #pragma unroll
        for (int i = 0; i < 24; ++i) {
            int idx = tid + i * 256;
            int j = idx / 96, rem = idx % 96;
            float w = Wc[(size_t)(oy + j) * 768 + c0 * 3 + rem];
            if (rem % 3 == 1)
                w += Wm[(size_t)(oy + j) * 512 + 256 + c0 + (rem - 1) / 3];
            Ws[rem * 68 + j] = w;
        }
        __syncthreads();
        #pragma unroll 4
        for (int cc = 0; cc < 32; ++cc) {
            float xs[6];
            float4 a = *(const float4*)&Xs[cc * 72 + tB];
            float2 a2 = *(const float2*)&Xs[cc * 72 + tB + 4];
            xs[0] = a.x; xs[1] = a.y; xs[2] = a.z; xs[3] = a.w; xs[4] = a2.x; xs[5] = a2.y;
            #pragma unroll
            for (int kh = 0; kh < 3; ++kh) {
                float4 w = *(const float4*)&Ws[(cc * 3 + kh) * 68 + oB];
                float wv[4] = {w.x, w.y, w.z, w.w};
                #pragma unroll
                for (int tt = 0; tt < 4; ++tt)
                    #pragma unroll
                    for (int oo = 0; oo < 4; ++oo) acc[tt][oo] += xs[tt + kh] * wv[oo];
            }
        }
    }
    for (int tt = 0; tt < 4; ++tt) {
        float4 v;
        float* vv = (float*)&v;
        #pragma unroll
        for (int oo = 0; oo < 4; ++oo) {
            int o = oy + oB + oo;
            vv[oo] = acc[tt][oo] + bc[o] + bm[o];
        }
        *(float4*)&E[((size_t)b * NT + tx + tB + tt) * 256 + oy + oB] = v;
    }
}

// wave-level sorted-top10 insert scan (proven correct; tie semantics match jax.lax.top_k)
__device__ __forceinline__ void topk_scan(const double* __restrict__ Dfrow, int jbase,
                                          unsigned long long validmask,
                                          volatile double* val, volatile int* idx, int lane) {
    double d = Dfrow[lane];
    double m10 = val[9];
    unsigned long long mask = __ballot(d < m10) & validmask;
    int guard = 0;
    while (mask && guard < 64) {
        ++guard;
        int bit = __ffsll((unsigned long long)mask) - 1;
        mask &= mask - 1;
        double vv = Dfrow[bit];
        double cur9 = val[9];
        if (!(vv < cur9)) continue;
        int jj = jbase + bit;
        double ev = (lane < 10) ? val[lane] : 0.0;
        int ej = (lane < 10) ? idx[lane] : 0;
        unsigned long long le = __ballot((lane < 10) && (ev <= vv));
        int pos = __popcll(le);
        double pv = (lane >= 1 && lane < 10) ? val[lane - 1] : 0.0;
        int pj = (lane >= 1 && lane < 10) ? idx[lane - 1] : 0;
        if (lane < 10) {
            val[lane] = (lane < pos) ? ev : ((lane == pos) ? vv : pv);
            idx[lane] = (lane < pos) ? ej : ((lane == pos) ? jj : pj);
        }
    }
}

// ---- MFMA-f64 distance core: 32 queries x 64 keys per k0 step ----
// v_mfma_f64_16x16x4 (K=4 multi-pass shape, per AMD Matrix-Cores lab notes):
//   A[m][k]: lane = m + 16k;  B[k][n]: lane = n + 16k
//   D: reg r, lane l -> row = (l>>4) + 4*r  (INTERLEAVED - not the K=32 blocked rule), col = l&15
#define XQ_S 33
#define XK_S 65

// ---------------- kernel 4: fp64 MFMA distances + unrestricted top-10 per row ----------------
__global__ __launch_bounds__(256) void k_knn(const float* __restrict__ x, const double* __restrict__ sq,
                                             int* __restrict__ nb) {
    __shared__ __align__(16) float Xq[256 * XQ_S];
    __shared__ __align__(16) float Xk[32 * XK_S];
    __shared__ __align__(16) double Df[32 * 64];
    __shared__ double Lv[32 * 10];
    __shared__ int Li[32 * 10];
    __shared__ double Sq[32];
    __shared__ double Sk[64];
    int q0 = blockIdx.x * 32;
    int b = blockIdx.y;
    int tid = threadIdx.x;
    int lane = tid & 63, wave = tid >> 6;
    for (int i = tid; i < 320; i += 256) { Lv[i] = INFINITY; Li[i] = 0; }
    if (tid < 32) Sq[tid] = sq[b * NT + q0 + tid];
    #pragma unroll
    for (int i = 0; i < 32; ++i) {
        int idx = tid + i * 256;
        int c = idx >> 5, q = idx & 31;
        Xq[c * XQ_S + q] = x[((size_t)b * NC + c) * NT + q0 + q];
    }
    __syncthreads();
    int qt  = (wave & 1) * 16;       // query sub-tile base (0/16)
    int ktb = (wave >> 1) * 32;      // key sub-tile base (0/32)
    int csub = lane >> 4;            // k index within MFMA (0..3)
    int l15 = lane & 15;
    int qrow = qt + l15;             // A row
    int kc0 = ktb + l15;             // B col, tile 0
    int kc1 = ktb + 16 + l15;        // B col, tile 1
    for (int k0 = 0; k0 < NT; k0 += 64) {
        dbl4 acc0 = {0.0, 0.0, 0.0, 0.0};
        dbl4 acc1 = {0.0, 0.0, 0.0, 0.0};
        if (tid < 64) Sk[tid] = sq[b * NT + k0 + tid];
        for (int cb = 0; cb < 256; cb += 32) {
            __syncthreads();
            #pragma unroll
            for (int i = 0; i < 8; ++i) {
                int idx = tid + i * 256;
                int c = idx >> 6, k = idx & 63;
                Xk[c * XK_S + k] = x[((size_t)b * NC + cb + c) * NT + k0 + k];
            }
            __syncthreads();
            #pragma unroll
            for (int c4 = 0; c4 < 32; c4 += 4) {
                double a  = (double)Xq[(cb + c4 + csub) * XQ_S + qrow];
                double b0 = (double)Xk[(c4 + csub) * XK_S + kc0];
                double b1 = (double)Xk[(c4 + csub) * XK_S + kc1];
                acc0 = __builtin_amdgcn_mfma_f64_16x16x4f64(a, b0, acc0, 0, 0, 0);
                acc1 = __builtin_amdgcn_mfma_f64_16x16x4f64(a, b1, acc1, 0, 0, 0);
            }
        }
        #pragma unroll
        for (int bb = 0; bb < 4; ++bb) {
            int m = qt + csub + bb * 4;   // FIX: interleaved K=4 C/D layout (row = group + 4*reg)
            Df[m * 64 + kc0] = Sq[m] + Sk[kc0] - 2.0 * acc0[bb];
            Df[m * 64 + kc1] = Sq[m] + Sk[kc1] - 2.0 * acc1[bb];
        }
        __syncthreads();
        for (int rr = 0; rr < 8; ++rr) {
            int r = wave * 8 + rr;
            topk_scan(&Df[r * 64], k0, ~0ull, &Lv[r * 10], &Li[r * 10], lane);
        }
        __syncthreads();
    }
    for (int i = tid; i < 320; i += 256)
        nb[((size_t)b * NT + q0 + i / 10) * 10 + (i % 10)] = Li[i];
}

// ---------------- kernel 4b: restricted re-selection (short batches, rows i >= thr) ----------------
__global__ __launch_bounds__(256) void k_knn2(const float* __restrict__ x, const double* __restrict__ sq,
                                              const int* __restrict__ nf, int* __restrict__ nb) {
    __shared__ __align__(16) float Xq[256 * XQ_S];
    __shared__ __align__(16) float Xk[32 * XK_S];
    __shared__ __align__(16) double Df[32 * 64];
    __shared__ double Lv[32 * 10];
    __shared__ int Li[32 * 10];
    __shared__ double Sq[32];
    __shared__ double Sk[64];
    int b = blockIdx.y;
    int n = load_nf(nf, b);
    if (n > 819) return;
    int thr = n + 20;
    int q0 = blockIdx.x * 32;
    if (q0 + 31 < thr) return;
    int tid = threadIdx.x;
    int lane = tid & 63, wave = tid >> 6;
    for (int i = tid; i < 320; i += 256) { Lv[i] = INFINITY; Li[i] = 0; }
    if (tid < 32) Sq[tid] = sq[b * NT + q0 + tid];
    #pragma unroll
    for (int i = 0; i < 32; ++i) {
        int idx = tid + i * 256;
        int c = idx >> 5, q = idx & 31;
        Xq[c * XQ_S + q] = x[((size_t)b * NC + c) * NT + q0 + q];
    }
    __syncthreads();
    int qt  = (wave & 1) * 16;
    int ktb = (wave >> 1) * 32;
    int csub = lane >> 4;
    int l15 = lane & 15;
    int qrow = qt + l15;
    int kc0 = ktb + l15;
    int kc1 = ktb + 16 + l15;
    for (int k0 = 0; k0 < thr; k0 += 64) {
        dbl4 acc0 = {0.0, 0.0, 0.0, 0.0};
        dbl4 acc1 = {0.0, 0.0, 0.0, 0.0};
        if (tid < 64) Sk[tid] = sq[b * NT + k0 + tid];
        for (int cb = 0; cb < 256; cb += 32) {
            __syncthreads();
            #pragma unroll
            for (int i = 0; i < 8; ++i) {
                int idx = tid + i * 256;
                int c = idx >> 6, k = idx & 63;
                Xk[c * XK_S + k] = x[((size_t)b * NC + cb + c) * NT + k0 + k];
            }
            __syncthreads();
            #pragma unroll
            for (int c4 = 0; c4 < 32; c4 += 4) {
                double a  = (double)Xq[(cb + c4 + csub) * XQ_S + qrow];
                double b0 = (double)Xk[(c4 + csub) * XK_S + kc0];
                double b1 = (double)Xk[(c4 + csub) * XK_S + kc1];
                acc0 = __builtin_amdgcn_mfma_f64_16x16x4f64(a, b0, acc0, 0, 0, 0);
                acc1 = __builtin_amdgcn_mfma_f64_16x16x4f64(a, b1, acc1, 0, 0, 0);
            }
        }
        #pragma unroll
        for (int bb = 0; bb < 4; ++bb) {
            int m = qt + csub + bb * 4;   // FIX: interleaved K=4 C/D layout
            Df[m * 64 + kc0] = Sq[m] + Sk[kc0] - 2.0 * acc0[bb];
            Df[m * 64 + kc1] = Sq[m] + Sk[kc1] - 2.0 * acc1[bb];
        }
        __syncthreads();
        unsigned long long vm = __ballot((k0 + lane) < thr);
        for (int rr = 0; rr < 8; ++rr) {
            int r = wave * 8 + rr;
            topk_scan(&Df[r * 64], k0, vm, &Lv[r * 10], &Li[r * 10], lane);
        }
        __syncthreads();
    }
    for (int rr = 0; rr < 8; ++rr) {
        int r = wave * 8 + rr;
        int i = q0 + r;
        if (i >= thr) {
            int e = (lane < 10) ? Li[r * 10 + lane] : -1;
            bool keep = lane < 10;
            #pragma unroll
            for (int s = 0; s < 5; ++s) {
                int f = nb[((size_t)b * NT + i) * 10 + s];
                keep = keep && (e != f);
            }
            unsigned long long km = __ballot(keep);
            int rank = __popcll(km & ((1ull << lane) - 1ull));
            if (keep && rank < 5) nb[((size_t)b * NT + i) * 10 + 5 + rank] = e;
        }
    }
}

// ---------------- kernel 5: epilogue — gather-max + E add + relu + pair max-pool ----------------
__global__ __launch_bounds__(256) void k_epi(const float* __restrict__ A, const float* __restrict__ E,
                                             const int* __restrict__ nb, float* __restrict__ out) {
    __shared__ float buf[256 * 33];
    int p0 = blockIdx.x * 32;
    int b = blockIdx.y;
    int o = threadIdx.x;
    for (int pp = 0; pp < 32; ++pp) {
        int p = p0 + pp;
        float vmax = 0.f;
        #pragma unroll
        for (int tt = 0; tt < 2; ++tt) {
            int t = p * 2 + tt;
            const int* nrow = &nb[((size_t)b * NT + t) * 10];
            float gm = -FLT_MAX;
            #pragma unroll
            for (int k = 0; k < 10; ++k) {
                int t2 = nrow[k] & (NT - 1);
                gm = fmaxf(gm, A[((size_t)b * NT + t2) * 256 + o]);
            }
            float v = E[((size_t)b * NT + t) * 256 + o] + gm;
            v = fmaxf(v, 0.f);
            vmax = (tt == 0) ? v : fmaxf(vmax, v);
        }
        buf[o * 33 + pp] = vmax;
    }
    __syncthreads();
    #pragma unroll
    for (int i = 0; i < 32; ++i) {
        int idx = threadIdx.x + i * 256;
        int oo = idx >> 5, pp = idx & 31;
        out[((size_t)b * 256 + oo) * 1024 + p0 + pp] = buf[oo * 33 + pp];
    }
}

extern "C" void kernel_launch(void* const* d_in, const int* in_sizes, int n_in,
                              void* d_out, int out_size, void* d_ws, size_t ws_size,
                              hipStream_t stream) {
    const float* x  = (const float*)d_in[0];
    const int*   nf = (const int*)d_in[1];
    const float* Wc = (const float*)d_in[2];
    const float* bc = (const float*)d_in[3];
    const float* Wm = (const float*)d_in[4];
    const float* bm = (const float*)d_in[5];
    float* out = (float*)d_out;
    char* ws = (char*)d_ws;
    double* sq = (double*)(ws + SQ_OFF);
    float* A   = (float*)(ws + A_OFF);
    float* E   = (float*)(ws + E_OFF);
    int* nb    = (int*)(ws + NB_OFF);

    k_sq<<<dim3(64), dim3(256), 0, stream>>>(x, sq);
    k_agemm<<<dim3(32, 4, 8), dim3(256), 0, stream>>>(x, Wm, A);
    k_conv<<<dim3(32, 4, 8), dim3(256), 0, stream>>>(x, Wc, bc, Wm, bm, E);
    k_knn<<<dim3(64, 8), dim3(256), 0, stream>>>(x, sq, nb);
    k_knn2<<<dim3(64, 8), dim3(256), 0, stream>>>(x, sq, nf, nb);
    k_epi<<<dim3(32, 8), dim3(256), 0, stream>>>(A, E, nb, out);
}

// Round 7
// 1321.619 us; speedup vs baseline: 2.7417x; 1.0817x over previous
//
#include <hip/hip_runtime.h>
#include <math.h>
#include <float.h>

#define NC 256
#define NT 2048
#define KNN 10

typedef __attribute__((ext_vector_type(4))) double dbl4;

// ws layout (bytes), total 34,340,864 (~32.8 MB):
#define SQ_OFF 0
#define A_OFF  131072
#define E_OFF  16908288
#define NB_OFF 33685504

// num_frms may be int32 or int64 depending on jax_enable_x64 in the harness.
__device__ __forceinline__ int load_nf(const int* __restrict__ nf, int b) {
    bool is64 = (nf[1] == 0) & (nf[3] == 0) & (nf[5] == 0) & (nf[7] == 0);
    return is64 ? nf[2 * b] : nf[b];
}

// ---------------- kernel 1: sq[b][t] = sum_c x[b][c][t]^2 (fp64) ----------------
__global__ __launch_bounds__(256) void k_sq(const float* __restrict__ x, double* __restrict__ sq) {
    int b = blockIdx.x >> 3;
    int t = ((blockIdx.x & 7) << 8) + threadIdx.x;
    const float* xp = x + (size_t)b * NC * NT + t;
    double a = 0.0;
    for (int c = 0; c < NC; ++c) { double v = (double)xp[(size_t)c * NT]; a = fma(v, v, a); }
    sq[b * NT + t] = a;
}

// ---------------- kernel 2: A[b][t][o] = sum_c x[b][c][t] * W_mlp[o][c]  (neighbor half) ----------------
__global__ __launch_bounds__(256) void k_agemm(const float* __restrict__ x, const float* __restrict__ Wm,
                                               float* __restrict__ A) {
    __shared__ __align__(16) float Xs[64 * 68];
    __shared__ __align__(16) float Ws[64 * 68];
    int tx = blockIdx.x * 64;
    int oy = blockIdx.y * 64;
    int b = blockIdx.z;
    int tid = threadIdx.x;
    int tB = (tid >> 4) * 4;
    int oB = (tid & 15) * 4;
    float acc[4][4] = {};
    for (int c0 = 0; c0 < 256; c0 += 64) {
        __syncthreads();
        #pragma unroll
        for (int i = 0; i < 16; ++i) {
            int idx = tid + i * 256;
            int hi = idx >> 6, lo = idx & 63;
            Xs[hi * 68 + lo] = x[((size_t)b * NC + c0 + hi) * NT + tx + lo];
            Ws[lo * 68 + hi] = Wm[(size_t)(oy + hi) * 512 + c0 + lo];
        }
        __syncthreads();
        #pragma unroll 8
        for (int cc = 0; cc < 64; ++cc) {
            float4 xa = *(const float4*)&Xs[cc * 68 + tB];
            float4 wb = *(const float4*)&Ws[cc * 68 + oB];
            float xv[4] = {xa.x, xa.y, xa.z, xa.w};
            float wv[4] = {wb.x, wb.y, wb.z, wb.w};
            #pragma unroll
            for (int i = 0; i < 4; ++i)
                #pragma unroll
                for (int j = 0; j < 4; ++j) acc[i][j] += xv[i] * wv[j];
        }
    }
    for (int i = 0; i < 4; ++i) {
        float4 v = {acc[i][0], acc[i][1], acc[i][2], acc[i][3]};
        *(float4*)&A[((size_t)b * NT + tx + tB + i) * 256 + oy + oB] = v;
    }
}

// ---------------- kernel 3: E[b][t][o] = conv1d + folded center-tap MLP half + biases ----------------
__global__ __launch_bounds__(256) void k_conv(const float* __restrict__ x, const float* __restrict__ Wc,
                                              const float* __restrict__ bc, const float* __restrict__ Wm,
                                              const float* __restrict__ bm, float* __restrict__ E) {
    __shared__ __align__(16) float Xs[32 * 72];
    __shared__ __align__(16) float Ws[96 * 68];
    int tx = blockIdx.x * 64;
    int oy = blockIdx.y * 64;
    int b = blockIdx.z;
    int tid = threadIdx.x;
    int tB = (tid >> 4) * 4;
    int oB = (tid & 15) * 4;
    float acc[4][4] = {};
    for (int c0 = 0; c0 < 256; c0 += 32) {
        __syncthreads();
        #pragma unroll
        for (int i = 0; i < 9; ++i) {
            int idx = tid + i * 256;
            if (idx < 32 * 66) {
                int c = idx / 66, j = idx % 66;
                int g = tx - 1 + j;
                float v = (g >= 0 && g < NT) ? x[((size_t)b * NC + c0 + c) * NT + g] : 0.f;
                Xs[c * 72 + j] = v;
            }
        }
        #pragma unroll
        for (int i = 0; i < 24; ++i) {
            int idx = tid + i * 256;
            int j = idx / 96, rem = idx % 96;
            float w = Wc[(size_t)(oy + j) * 768 + c0 * 3 + rem];
            if (rem % 3 == 1)
                w += Wm[(size_t)(oy + j) * 512 + 256 + c0 + (rem - 1) / 3];
            Ws[rem * 68 + j] = w;
        }
        __syncthreads();
        #pragma unroll 4
        for (int cc = 0; cc < 32; ++cc) {
            float xs[6];
            float4 a = *(const float4*)&Xs[cc * 72 + tB];
            float2 a2 = *(const float2*)&Xs[cc * 72 + tB + 4];
            xs[0] = a.x; xs[1] = a.y; xs[2] = a.z; xs[3] = a.w; xs[4] = a2.x; xs[5] = a2.y;
            #pragma unroll
            for (int kh = 0; kh < 3; ++kh) {
                float4 w = *(const float4*)&Ws[(cc * 3 + kh) * 68 + oB];
                float wv[4] = {w.x, w.y, w.z, w.w};
                #pragma unroll
                for (int tt = 0; tt < 4; ++tt)
                    #pragma unroll
                    for (int oo = 0; oo < 4; ++oo) acc[tt][oo] += xs[tt + kh] * wv[oo];
            }
        }
    }
    for (int tt = 0; tt < 4; ++tt) {
        float4 v;
        float* vv = (float*)&v;
        #pragma unroll
        for (int oo = 0; oo < 4; ++oo) {
            int o = oy + oB + oo;
            vv[oo] = acc[tt][oo] + bc[o] + bm[o];
        }
        *(float4*)&E[((size_t)b * NT + tx + tB + tt) * 256 + oy + oB] = v;
    }
}

// wave-level sorted-top10 insert scan (proven correct; tie semantics match jax.lax.top_k)
__device__ __forceinline__ void topk_scan(const double* __restrict__ Dfrow, int jbase,
                                          unsigned long long validmask,
                                          volatile double* val, volatile int* idx, int lane) {
    double d = Dfrow[lane];
    double m10 = val[9];
    unsigned long long mask = __ballot(d < m10) & validmask;
    int guard = 0;
    while (mask && guard < 64) {
        ++guard;
        int bit = __ffsll((unsigned long long)mask) - 1;
        mask &= mask - 1;
        double vv = Dfrow[bit];
        double cur9 = val[9];
        if (!(vv < cur9)) continue;
        int jj = jbase + bit;
        double ev = (lane < 10) ? val[lane] : 0.0;
        int ej = (lane < 10) ? idx[lane] : 0;
        unsigned long long le = __ballot((lane < 10) && (ev <= vv));
        int pos = __popcll(le);
        double pv = (lane >= 1 && lane < 10) ? val[lane - 1] : 0.0;
        int pj = (lane >= 1 && lane < 10) ? idx[lane - 1] : 0;
        if (lane < 10) {
            val[lane] = (lane < pos) ? ev : ((lane == pos) ? vv : pv);
            idx[lane] = (lane < pos) ? ej : ((lane == pos) ? jj : pj);
        }
    }
}

// ---- MFMA-f64 distance core: 32 queries x 64 keys per k0 step ----
// v_mfma_f64_16x16x4 (K=4 multi-pass shape):
//   A[m][k]: lane = m + 16k;  B[k][n]: lane = n + 16k
//   D: reg r, lane l -> row = (l>>4) + 4*r (interleaved), col = l&15   [verified round 6]
// Pipeline: Xk double-buffered; chunk ch+1 written from regs & chunk ch+2 global-prefetched
// while MFMA consumes chunk ch. One barrier per chunk (5 per k0 vs 10 before).
#define XQ_S 33
#define XK_S 65

// ---------------- kernel 4: fp64 MFMA distances + unrestricted top-10 per row ----------------
__global__ __launch_bounds__(256) void k_knn(const float* __restrict__ x, const double* __restrict__ sq,
                                             int* __restrict__ nb) {
    __shared__ __align__(16) float Xq[256 * XQ_S];
    __shared__ __align__(16) float Xk[2][32 * XK_S];
    __shared__ __align__(16) double Df[32 * 64];
    __shared__ double Lv[32 * 10];
    __shared__ int Li[32 * 10];
    __shared__ double Sq[32];
    __shared__ double Sk[64];
    int q0 = blockIdx.x * 32;
    int b = blockIdx.y;
    int tid = threadIdx.x;
    int lane = tid & 63, wave = tid >> 6;
    const float* xb = x + (size_t)b * NC * NT;
    for (int i = tid; i < 320; i += 256) { Lv[i] = INFINITY; Li[i] = 0; }
    if (tid < 32) Sq[tid] = sq[b * NT + q0 + tid];
    #pragma unroll
    for (int i = 0; i < 32; ++i) {
        int idx = tid + i * 256;
        int c = idx >> 5, q = idx & 31;
        Xq[c * XQ_S + q] = x[((size_t)b * NC + c) * NT + q0 + q];
    }
    // staging geometry per chunk (32ch x 64key): element i -> channel wave+4i, key lane
    float pf[8];
    const int nch = (NT / 64) * 8;
    // prologue: chunk0 -> buf0; prefetch chunk1 into regs
    #pragma unroll
    for (int i = 0; i < 8; ++i) pf[i] = xb[(size_t)(wave + 4 * i) * NT + lane];
    #pragma unroll
    for (int i = 0; i < 8; ++i) Xk[0][(wave + 4 * i) * XK_S + lane] = pf[i];
    #pragma unroll
    for (int i = 0; i < 8; ++i) pf[i] = xb[(size_t)(32 + wave + 4 * i) * NT + lane];
    __syncthreads();
    int qt  = (wave & 1) * 16;
    int ktb = (wave >> 1) * 32;
    int csub = lane >> 4;
    int l15 = lane & 15;
    int qrow = qt + l15;
    int kc0 = ktb + l15;
    int kc1 = ktb + 16 + l15;
    int ch = 0;
    for (int k0 = 0; k0 < NT; k0 += 64) {
        dbl4 acc0 = {0.0, 0.0, 0.0, 0.0};
        dbl4 acc1 = {0.0, 0.0, 0.0, 0.0};
        if (tid < 64) Sk[tid] = sq[b * NT + k0 + tid];
        #pragma unroll
        for (int cc = 0; cc < 8; ++cc) {
            int cur = ch & 1;
            int cb = cc << 5;
            if (ch + 1 < nch) {               // write prefetched chunk ch+1 -> other buffer
                #pragma unroll
                for (int i = 0; i < 8; ++i) Xk[cur ^ 1][(wave + 4 * i) * XK_S + lane] = pf[i];
            }
            if (ch + 2 < nch) {               // issue global prefetch for chunk ch+2
                int n2 = ch + 2;
                int nk0 = (n2 >> 3) << 6, ncb = (n2 & 7) << 5;
                #pragma unroll
                for (int i = 0; i < 8; ++i) pf[i] = xb[(size_t)(ncb + wave + 4 * i) * NT + nk0 + lane];
            }
            #pragma unroll
            for (int c4 = 0; c4 < 32; c4 += 4) {
                double a  = (double)Xq[(cb + c4 + csub) * XQ_S + qrow];
                double b0 = (double)Xk[cur][(c4 + csub) * XK_S + kc0];
                double b1 = (double)Xk[cur][(c4 + csub) * XK_S + kc1];
                acc0 = __builtin_amdgcn_mfma_f64_16x16x4f64(a, b0, acc0, 0, 0, 0);
                acc1 = __builtin_amdgcn_mfma_f64_16x16x4f64(a, b1, acc1, 0, 0, 0);
            }
            ++ch;
            if (cc < 7) __syncthreads();
        }
        #pragma unroll
        for (int bb = 0; bb < 4; ++bb) {
            int m = qt + csub + bb * 4;       // interleaved K=4 C/D layout
            Df[m * 64 + kc0] = Sq[m] + Sk[kc0] - 2.0 * acc0[bb];
            Df[m * 64 + kc1] = Sq[m] + Sk[kc1] - 2.0 * acc1[bb];
        }
        __syncthreads();                      // covers Df + next-k0 chunk0 staging
        for (int rr = 0; rr < 8; ++rr) {
            int r = wave * 8 + rr;
            topk_scan(&Df[r * 64], k0, ~0ull, &Lv[r * 10], &Li[r * 10], lane);
        }
        __syncthreads();
    }
    for (int i = tid; i < 320; i += 256)
        nb[((size_t)b * NT + q0 + i / 10) * 10 + (i % 10)] = Li[i];
}

// ---------------- kernel 4b: restricted re-selection (short batches, rows i >= thr) ----------------
__global__ __launch_bounds__(256) void k_knn2(const float* __restrict__ x, const double* __restrict__ sq,
                                              const int* __restrict__ nf, int* __restrict__ nb) {
    __shared__ __align__(16) float Xq[256 * XQ_S];
    __shared__ __align__(16) float Xk[2][32 * XK_S];
    __shared__ __align__(16) double Df[32 * 64];
    __shared__ double Lv[32 * 10];
    __shared__ int Li[32 * 10];
    __shared__ double Sq[32];
    __shared__ double Sk[64];
    int b = blockIdx.y;
    int n = load_nf(nf, b);
    if (n > 819) return;
    int thr = n + 20;
    int q0 = blockIdx.x * 32;
    if (q0 + 31 < thr) return;
    int tid = threadIdx.x;
    int lane = tid & 63, wave = tid >> 6;
    const float* xb = x + (size_t)b * NC * NT;
    for (int i = tid; i < 320; i += 256) { Lv[i] = INFINITY; Li[i] = 0; }
    if (tid < 32) Sq[tid] = sq[b * NT + q0 + tid];
    #pragma unroll
    for (int i = 0; i < 32; ++i) {
        int idx = tid + i * 256;
        int c = idx >> 5, q = idx & 31;
        Xq[c * XQ_S + q] = x[((size_t)b * NC + c) * NT + q0 + q];
    }
    float pf[8];
    const int nch = ((thr + 63) >> 6) * 8;
    #pragma unroll
    for (int i = 0; i < 8; ++i) pf[i] = xb[(size_t)(wave + 4 * i) * NT + lane];
    #pragma unroll
    for (int i = 0; i < 8; ++i) Xk[0][(wave + 4 * i) * XK_S + lane] = pf[i];
    if (nch > 1) {
        #pragma unroll
        for (int i = 0; i < 8; ++i) pf[i] = xb[(size_t)(32 + wave + 4 * i) * NT + lane];
    }
    __syncthreads();
    int qt  = (wave & 1) * 16;
    int ktb = (wave >> 1) * 32;
    int csub = lane >> 4;
    int l15 = lane & 15;
    int qrow = qt + l15;
    int kc0 = ktb + l15;
    int kc1 = ktb + 16 + l15;
    int ch = 0;
    for (int k0 = 0; k0 < thr; k0 += 64) {
        dbl4 acc0 = {0.0, 0.0, 0.0, 0.0};
        dbl4 acc1 = {0.0, 0.0, 0.0, 0.0};
        if (tid < 64) Sk[tid] = sq[b * NT + k0 + tid];
        #pragma unroll
        for (int cc = 0; cc < 8; ++cc) {
            int cur = ch & 1;
            int cb = cc << 5;
            if (ch + 1 < nch) {
                #pragma unroll
                for (int i = 0; i < 8; ++i) Xk[cur ^ 1][(wave + 4 * i) * XK_S + lane] = pf[i];
            }
            if (ch + 2 < nch) {
                int n2 = ch + 2;
                int nk0 = (n2 >> 3) << 6, ncb = (n2 & 7) << 5;
                #pragma unroll
                for (int i = 0; i < 8; ++i) pf[i] = xb[(size_t)(ncb + wave + 4 * i) * NT + nk0 + lane];
            }
            #pragma unroll
            for (int c4 = 0; c4 < 32; c4 += 4) {
                double a  = (double)Xq[(cb + c4 + csub) * XQ_S + qrow];
                double b0 = (double)Xk[cur][(c4 + csub) * XK_S + kc0];
                double b1 = (double)Xk[cur][(c4 + csub) * XK_S + kc1];
                acc0 = __builtin_amdgcn_mfma_f64_16x16x4f64(a, b0, acc0, 0, 0, 0);
                acc1 = __builtin_amdgcn_mfma_f64_16x16x4f64(a, b1, acc1, 0, 0, 0);
            }
            ++ch;
            if (cc < 7) __syncthreads();
        }
        #pragma unroll
        for (int bb = 0; bb < 4; ++bb) {
            int m = qt + csub + bb * 4;
            Df[m * 64 + kc0] = Sq[m] + Sk[kc0] - 2.0 * acc0[bb];
            Df[m * 64 + kc1] = Sq[m] + Sk[kc1] - 2.0 * acc1[bb];
        }
        __syncthreads();
        unsigned long long vm = __ballot((k0 + lane) < thr);
        for (int rr = 0; rr < 8; ++rr) {
            int r = wave * 8 + rr;
            topk_scan(&Df[r * 64], k0, vm, &Lv[r * 10], &Li[r * 10], lane);
        }
        __syncthreads();
    }
    for (int rr = 0; rr < 8; ++rr) {
        int r = wave * 8 + rr;
        int i = q0 + r;
        if (i >= thr) {
            int e = (lane < 10) ? Li[r * 10 + lane] : -1;
            bool keep = lane < 10;
            #pragma unroll
            for (int s = 0; s < 5; ++s) {
                int f = nb[((size_t)b * NT + i) * 10 + s];
                keep = keep && (e != f);
            }
            unsigned long long km = __ballot(keep);
            int rank = __popcll(km & ((1ull << lane) - 1ull));
            if (keep && rank < 5) nb[((size_t)b * NT + i) * 10 + 5 + rank] = e;
        }
    }
}

// ---------------- kernel 5: epilogue — gather-max + E add + relu + pair max-pool ----------------
__global__ __launch_bounds__(256) void k_epi(const float* __restrict__ A, const float* __restrict__ E,
                                             const int* __restrict__ nb, float* __restrict__ out) {
    __shared__ float buf[256 * 33];
    int p0 = blockIdx.x * 32;
    int b = blockIdx.y;
    int o = threadIdx.x;
    for (int pp = 0; pp < 32; ++pp) {
        int p = p0 + pp;
        float vmax = 0.f;
        #pragma unroll
        for (int tt = 0; tt < 2; ++tt) {
            int t = p * 2 + tt;
            const int* nrow = &nb[((size_t)b * NT + t) * 10];
            float gm = -FLT_MAX;
            #pragma unroll
            for (int k = 0; k < 10; ++k) {
                int t2 = nrow[k] & (NT - 1);
                gm = fmaxf(gm, A[((size_t)b * NT + t2) * 256 + o]);
            }
            float v = E[((size_t)b * NT + t) * 256 + o] + gm;
            v = fmaxf(v, 0.f);
            vmax = (tt == 0) ? v : fmaxf(vmax, v);
        }
        buf[o * 33 + pp] = vmax;
    }
    __syncthreads();
    #pragma unroll
    for (int i = 0; i < 32; ++i) {
        int idx = threadIdx.x + i * 256;
        int oo = idx >> 5, pp = idx & 31;
        out[((size_t)b * 256 + oo) * 1024 + p0 + pp] = buf[oo * 33 + pp];
    }
}

extern "C" void kernel_launch(void* const* d_in, const int* in_sizes, int n_in,
                              void* d_out, int out_size, void* d_ws, size_t ws_size,
                              hipStream_t stream) {
    const float* x  = (const float*)d_in[0];
    const int*   nf = (const int*)d_in[1];
    const float* Wc = (const float*)d_in[2];
    const float* bc = (const float*)d_in[3];
    const float* Wm = (const float*)d_in[4];
    const float* bm = (const float*)d_in[5];
    float* out = (float*)d_out;
    char* ws = (char*)d_ws;
    double* sq = (double*)(ws + SQ_OFF);
    float* A   = (float*)(ws + A_OFF);
    float* E   = (float*)(ws + E_OFF);
    int* nb    = (int*)(ws + NB_OFF);

    k_sq<<<dim3(64), dim3(256), 0, stream>>>(x, sq);
    k_agemm<<<dim3(32, 4, 8), dim3(256), 0, stream>>>(x, Wm, A);
    k_conv<<<dim3(32, 4, 8), dim3(256), 0, stream>>>(x, Wc, bc, Wm, bm, E);
    k_knn<<<dim3(64, 8), dim3(256), 0, stream>>>(x, sq, nb);
    k_knn2<<<dim3(64, 8), dim3(256), 0, stream>>>(x, sq, nf, nb);
    k_epi<<<dim3(32, 8), dim3(256), 0, stream>>>(A, E, nb, out);
}